// Round 6
// baseline (935.064 us; speedup 1.0000x reference)
//
#include <hip/hip_runtime.h>
#include <math.h>

typedef short bf16x8 __attribute__((ext_vector_type(8)));
typedef float f32x4 __attribute__((ext_vector_type(4)));
typedef unsigned short u16;

#define AS1 __attribute__((address_space(1)))
#define AS3 __attribute__((address_space(3)))

constexpr int kB = 16, kT = 1024, kS = 2048, kH = 1024;
constexpr long NTH = (long)kB * kT * kH;  // 16.8M elems
constexpr long NSH = (long)kB * kS * kH;  // 33.6M elems

// ---------------- bf16 helpers ----------------
__device__ __forceinline__ u16 bf16_rne(float x) {
    unsigned u = __float_as_uint(x);
    u += 0x7FFFu + ((u >> 16) & 1u);
    return (u16)(u >> 16);
}
__device__ __forceinline__ float bf16_f32(u16 h) {
    return __uint_as_float(((unsigned)h) << 16);
}
__device__ __forceinline__ void split2(float x, u16& hi, u16& lo) {
    hi = bf16_rne(x);
    lo = bf16_rne(x - bf16_f32(hi));
}

// =========================================================================
// CORE A (round-2, measured 217us/41%/0-conflict): 256x256xBK=64, 16x16x32,
// 2 barriers/tile, counted vmcnt(8). Swizzle: (row, byte c) at LDS byte
// row*128 + (c ^ ((row&7)<<4)); linear gll dest + inverse-swizzled source.
// =========================================================================
__device__ __forceinline__ void stage_mat(const u16* __restrict__ g, long ld,
                                          u16* lds, int t, int wave) {
#pragma unroll
    for (int c = 0; c < 4; ++c) {
        int u = c * 512 + t;          // 16B unit, 8 per 128B row
        int r = u >> 3, j = u & 7;
        const u16* src = g + (long)r * ld + ((j ^ (r & 7)) << 3);  // inverse swizzle
        u16* dst = lds + c * 4096 + wave * 512;                    // linear dest
        __builtin_amdgcn_global_load_lds((AS1 void*)src, (AS3 void*)dst, 16, 0, 0);
    }
}

__device__ __forceinline__ void tile_compute(const u16* As, const u16* Bs,
                                             f32x4 acc[8][4], int wr, int wc,
                                             int l15, int cbu0, int cbu1) {
    bf16x8 b[4][2];
#pragma unroll
    for (int j = 0; j < 4; ++j) {
        const u16* base = Bs + (wc * 64 + j * 16 + l15) * 64;
        b[j][0] = *(const bf16x8*)(base + cbu0);
        b[j][1] = *(const bf16x8*)(base + cbu1);
    }
#pragma unroll
    for (int qm = 0; qm < 2; ++qm) {
        bf16x8 a[4][2];
#pragma unroll
        for (int i = 0; i < 4; ++i) {
            const u16* base = As + (wr * 128 + qm * 64 + i * 16 + l15) * 64;
            a[i][0] = *(const bf16x8*)(base + cbu0);
            a[i][1] = *(const bf16x8*)(base + cbu1);
        }
        __builtin_amdgcn_s_setprio(1);
#pragma unroll
        for (int i = 0; i < 4; ++i)
#pragma unroll
            for (int j = 0; j < 4; ++j) {
                acc[qm * 4 + i][j] = __builtin_amdgcn_mfma_f32_16x16x32_bf16(
                    a[i][0], b[j][0], acc[qm * 4 + i][j], 0, 0, 0);
                acc[qm * 4 + i][j] = __builtin_amdgcn_mfma_f32_16x16x32_bf16(
                    a[i][1], b[j][1], acc[qm * 4 + i][j], 0, 0, 0);
            }
        __builtin_amdgcn_s_setprio(0);
    }
}

#define WAIT_VM(N)                                            \
    asm volatile("s_waitcnt vmcnt(" #N ")" ::: "memory");     \
    __builtin_amdgcn_s_barrier();                             \
    __builtin_amdgcn_sched_barrier(0);

#define POST_BARRIER()                                        \
    __builtin_amdgcn_sched_barrier(0);                        \
    __builtin_amdgcn_s_barrier();                             \
    __builtin_amdgcn_sched_barrier(0);

template <int NT, int TPS>
__device__ __forceinline__ void gemm_core(const u16* a0, const u16* a1, const u16* a2,
                                          long lda,
                                          const u16* b0, const u16* b1, const u16* b2,
                                          long ldb, f32x4 acc[8][4]) {
    __shared__ u16 As[2][256 * 64], Bs[2][256 * 64];
    const int t = threadIdx.x, lane = t & 63, wave = t >> 6;
    const int wr = wave >> 2, wc = wave & 3, l15 = lane & 15, quad = lane >> 4;
    const int swzb = (l15 & 7) << 4;
    const int cbu0 = ((quad * 16) ^ swzb) >> 1;        // u16 offset, k-half 0
    const int cbu1 = ((quad * 16 + 64) ^ swzb) >> 1;   // u16 offset, k-half 1

    auto srcA = [&](int kt) {
        int seg = kt / TPS;
        const u16* p = (seg == 0) ? a0 : (seg == 1 ? a1 : a2);
        return p + (long)(kt % TPS) * 64;
    };
    auto srcB = [&](int kt) {
        int seg = kt / TPS;
        const u16* p = (seg == 0) ? b0 : (seg == 1 ? b1 : b2);
        return p + (long)(kt % TPS) * 64;
    };

    stage_mat(srcA(0), lda, As[0], t, wave);
    stage_mat(srcB(0), ldb, Bs[0], t, wave);
    __builtin_amdgcn_sched_barrier(0);
    stage_mat(srcA(1), lda, As[1], t, wave);
    stage_mat(srcB(1), ldb, Bs[1], t, wave);
    __builtin_amdgcn_sched_barrier(0);

#pragma unroll 1
    for (int it = 0; it < NT / 2 - 1; ++it) {
        int kt = 2 * it;
        WAIT_VM(8)
        tile_compute(As[0], Bs[0], acc, wr, wc, l15, cbu0, cbu1);
        POST_BARRIER()
        stage_mat(srcA(kt + 2), lda, As[0], t, wave);
        stage_mat(srcB(kt + 2), ldb, Bs[0], t, wave);

        WAIT_VM(8)
        tile_compute(As[1], Bs[1], acc, wr, wc, l15, cbu0, cbu1);
        POST_BARRIER()
        stage_mat(srcA(kt + 3), lda, As[1], t, wave);
        stage_mat(srcB(kt + 3), ldb, Bs[1], t, wave);
    }
    WAIT_VM(8)
    tile_compute(As[0], Bs[0], acc, wr, wc, l15, cbu0, cbu1);
    WAIT_VM(0)
    tile_compute(As[1], Bs[1], acc, wr, wc, l15, cbu0, cbu1);
}

// =========================================================================
// CORE P4 (logits only): corrected 4-phase schedule.
// Reads:  P1: b[0..3]+a[0..3] (16 ds_read) -> B halves dead after P1-barrier
//         P2: a[4..7] (8 ds_read)          -> A halves dead after P2-barrier
// MFMA:   P1 Q(0,0)  P2 Q(0,1)  P3 Q(1,0)  P4 Q(1,1)   (16 each)
// Stages: P1: A-h0(j+1)->opp buf   P2: A-h1(j+1)->opp
//         P3: B-h0(j+2)->SAME buf (legal: B dead since P1-barrier)
//         P4: B-h1(j+2)->SAME buf
// Wait:   single vmcnt(4) at tile end: leaves exactly {B-h0,B-h1}(j+2) in
//         flight (4-6 phase lead); guarantees tile j+1 fully resident.
// Prologue: A0(0) A1(0) B0(0) B1(0) B0(1) B1(1); vmcnt(4).
// =========================================================================
template <int NT, int TPS>
__device__ __forceinline__ void gemm_core_p4(const u16* a0p, const u16* a1p,
                                             const u16* a2p, long lda,
                                             const u16* b0p, const u16* b1p,
                                             const u16* b2p, long ldb, f32x4 acc[8][4]) {
    __shared__ u16 As[2][256 * 64], Bs[2][256 * 64];
    const int t = threadIdx.x, lane = t & 63, wave = t >> 6;
    const int wr = wave >> 2, wc = wave & 3, l15 = lane & 15, quad = lane >> 4;
    const int swzb = (l15 & 7) << 4;
    const int cbu0 = ((quad * 16) ^ swzb) >> 1;
    const int cbu1 = ((quad * 16 + 64) ^ swzb) >> 1;

    auto srcA = [&](int kt) {
        int seg = kt / TPS;
        const u16* p = (seg == 0) ? a0p : (seg == 1 ? a1p : a2p);
        return p + (long)(kt % TPS) * 64;
    };
    auto srcB = [&](int kt) {
        int seg = kt / TPS;
        const u16* p = (seg == 0) ? b0p : (seg == 1 ? b1p : b2p);
        return p + (long)(kt % TPS) * 64;
    };
    // stage one 128x64 half-tile (16 KiB) = 2 gll/thread
    auto stageH = [&](const u16* g, long ld, int h, u16* bufbase) {
        const u16* gh = g + (long)h * 128 * ld;
        u16* region = bufbase + h * 8192;
#pragma unroll
        for (int cc = 0; cc < 2; ++cc) {
            int u = cc * 512 + t;
            int r = u >> 3, j8 = u & 7;
            const u16* src = gh + (long)r * ld + ((j8 ^ (r & 7)) << 3);
            u16* dst = region + cc * 4096 + wave * 512;
            __builtin_amdgcn_global_load_lds((AS1 void*)src, (AS3 void*)dst, 16, 0, 0);
        }
    };

    stageH(srcA(0), lda, 0, As[0]);
    stageH(srcA(0), lda, 1, As[0]);
    stageH(srcB(0), ldb, 0, Bs[0]);
    stageH(srcB(0), ldb, 1, Bs[0]);
    stageH(srcB(1), ldb, 0, Bs[1]);
    stageH(srcB(1), ldb, 1, Bs[1]);
    asm volatile("s_waitcnt vmcnt(4)" ::: "memory");
    __builtin_amdgcn_s_barrier();

#pragma unroll 1
    for (int j = 0; j < NT; ++j) {
        const int c = j & 1;
        const int jA = (j + 1 < NT) ? j + 1 : NT - 1;
        const int jB = (j + 2 < NT) ? j + 2 : NT - 1;
        const u16* As_c = As[c];
        const u16* Bs_c = Bs[c];
        bf16x8 aF[8][2], bF[4][2];

        // ---- P1: reads b[0..3] + a[0..3]; stage A-h0(j+1); MFMA Q(0,0)
#pragma unroll
        for (int n = 0; n < 4; ++n) {
            const u16* base = Bs_c + (wc * 64 + n * 16 + l15) * 64;
            bF[n][0] = *(const bf16x8*)(base + cbu0);
            bF[n][1] = *(const bf16x8*)(base + cbu1);
        }
#pragma unroll
        for (int i = 0; i < 4; ++i) {
            const u16* base = As_c + (wr * 128 + i * 16 + l15) * 64;
            aF[i][0] = *(const bf16x8*)(base + cbu0);
            aF[i][1] = *(const bf16x8*)(base + cbu1);
        }
        stageH(srcA(jA), lda, 0, As[c ^ 1]);
        __builtin_amdgcn_s_barrier();
        asm volatile("s_waitcnt lgkmcnt(0)" ::: "memory");
        __builtin_amdgcn_sched_barrier(0);
        __builtin_amdgcn_s_setprio(1);
#pragma unroll
        for (int i = 0; i < 4; ++i)
#pragma unroll
            for (int n = 0; n < 2; ++n) {
                acc[i][n] = __builtin_amdgcn_mfma_f32_16x16x32_bf16(
                    aF[i][0], bF[n][0], acc[i][n], 0, 0, 0);
                acc[i][n] = __builtin_amdgcn_mfma_f32_16x16x32_bf16(
                    aF[i][1], bF[n][1], acc[i][n], 0, 0, 0);
            }
        __builtin_amdgcn_s_setprio(0);
        __builtin_amdgcn_sched_barrier(0);
        __builtin_amdgcn_s_barrier();

        // ---- P2: reads a[4..7]; stage A-h1(j+1); MFMA Q(0,1)
#pragma unroll
        for (int i = 0; i < 4; ++i) {
            const u16* base = As_c + (wr * 128 + 64 + i * 16 + l15) * 64;
            aF[4 + i][0] = *(const bf16x8*)(base + cbu0);
            aF[4 + i][1] = *(const bf16x8*)(base + cbu1);
        }
        stageH(srcA(jA), lda, 1, As[c ^ 1]);
        __builtin_amdgcn_s_barrier();
        asm volatile("s_waitcnt lgkmcnt(0)" ::: "memory");
        __builtin_amdgcn_sched_barrier(0);
        __builtin_amdgcn_s_setprio(1);
#pragma unroll
        for (int i = 0; i < 4; ++i)
#pragma unroll
            for (int n = 0; n < 2; ++n) {
                acc[i][2 + n] = __builtin_amdgcn_mfma_f32_16x16x32_bf16(
                    aF[i][0], bF[2 + n][0], acc[i][2 + n], 0, 0, 0);
                acc[i][2 + n] = __builtin_amdgcn_mfma_f32_16x16x32_bf16(
                    aF[i][1], bF[2 + n][1], acc[i][2 + n], 0, 0, 0);
            }
        __builtin_amdgcn_s_setprio(0);
        __builtin_amdgcn_sched_barrier(0);
        __builtin_amdgcn_s_barrier();

        // ---- P3: stage B-h0(j+2) into same buf; MFMA Q(1,0)
        stageH(srcB(jB), ldb, 0, Bs[c]);
        __builtin_amdgcn_s_barrier();
        __builtin_amdgcn_s_setprio(1);
#pragma unroll
        for (int i = 0; i < 4; ++i)
#pragma unroll
            for (int n = 0; n < 2; ++n) {
                acc[4 + i][n] = __builtin_amdgcn_mfma_f32_16x16x32_bf16(
                    aF[4 + i][0], bF[n][0], acc[4 + i][n], 0, 0, 0);
                acc[4 + i][n] = __builtin_amdgcn_mfma_f32_16x16x32_bf16(
                    aF[4 + i][1], bF[n][1], acc[4 + i][n], 0, 0, 0);
            }
        __builtin_amdgcn_s_setprio(0);
        __builtin_amdgcn_sched_barrier(0);
        __builtin_amdgcn_s_barrier();

        // ---- P4: stage B-h1(j+2); MFMA Q(1,1); vmcnt(4); barrier
        stageH(srcB(jB), ldb, 1, Bs[c]);
        __builtin_amdgcn_s_barrier();
        __builtin_amdgcn_s_setprio(1);
#pragma unroll
        for (int i = 0; i < 4; ++i)
#pragma unroll
            for (int n = 0; n < 2; ++n) {
                acc[4 + i][2 + n] = __builtin_amdgcn_mfma_f32_16x16x32_bf16(
                    aF[4 + i][0], bF[2 + n][0], acc[4 + i][2 + n], 0, 0, 0);
                acc[4 + i][2 + n] = __builtin_amdgcn_mfma_f32_16x16x32_bf16(
                    aF[4 + i][1], bF[2 + n][1], acc[4 + i][2 + n], 0, 0, 0);
            }
        __builtin_amdgcn_s_setprio(0);
        __builtin_amdgcn_sched_barrier(0);
        asm volatile("s_waitcnt vmcnt(4)" ::: "memory");
        __builtin_amdgcn_s_barrier();
    }
}

// ---------------- GEMM kernels ----------------
// q = output @ attn_w^T in split precision: K' = 3H, segs (oh,awh),(ol,awh),(oh,awl)
__global__ __launch_bounds__(512, 2) void k_gemm_q(const u16* __restrict__ oh,
                                                   const u16* __restrict__ ol,
                                                   const u16* __restrict__ awh,
                                                   const u16* __restrict__ awl,
                                                   u16* __restrict__ Qhi,
                                                   u16* __restrict__ Qlo) {
    const long bm = (long)blockIdx.y * 256, bn = (long)blockIdx.x * 256;
    f32x4 acc[8][4] = {};
    gemm_core<48, 16>(oh + bm * kH, ol + bm * kH, oh + bm * kH, kH,
                      awh + bn * kH, awh + bn * kH, awl + bn * kH, kH, acc);
    const int t = threadIdx.x, lane = t & 63, wave = t >> 6;
    const int wr = wave >> 2, wc = wave & 3, l15 = lane & 15, quad = lane >> 4;
#pragma unroll
    for (int i = 0; i < 8; ++i)
#pragma unroll
        for (int j = 0; j < 4; ++j)
#pragma unroll
            for (int r = 0; r < 4; ++r) {
                long m = bm + wr * 128 + i * 16 + quad * 4 + r;
                long n = bn + wc * 64 + j * 16 + l15;
                float v = acc[i][j][r];
                u16 h = bf16_rne(v);
                Qhi[m * kH + n] = h;
                Qlo[m * kH + n] = bf16_rne(v - bf16_f32(h));
            }
}

// logits = q @ ctx^T per batch, split: K' = 3H, segs (qh,ch),(ql,ch),(qh,cl)
// NEW P4 core. 1D grid 512, XCD-aware decode: each XCD owns 2 whole batches.
__global__ __launch_bounds__(512, 2) void k_gemm_logits(const u16* __restrict__ Qh,
                                                        const u16* __restrict__ Ql,
                                                        const u16* __restrict__ Ch,
                                                        const u16* __restrict__ Cl,
                                                        float* __restrict__ Cout) {
    const int l = blockIdx.x;
    const int xcd = l & 7, slot = l >> 3;
    const int z = xcd + ((slot >> 5) << 3);
    const int inner = slot & 31;
    const long bn = (long)(inner & 7) * 256;   // S tiles (8)
    const long bm = (long)(inner >> 3) * 256;  // T tiles (4)
    const u16* qh = Qh + (long)z * kT * kH + bm * kH;
    const u16* ql = Ql + (long)z * kT * kH + bm * kH;
    const u16* ch = Ch + (long)z * kS * kH + bn * kH;
    const u16* cl = Cl + (long)z * kS * kH + bn * kH;
    f32x4 acc[8][4] = {};
    gemm_core_p4<48, 16>(qh, ql, qh, kH, ch, ch, cl, kH, acc);
    float* C = Cout + (long)z * kT * kS;
    const int t = threadIdx.x, lane = t & 63, wave = t >> 6;
    const int wr = wave >> 2, wc = wave & 3, l15 = lane & 15, quad = lane >> 4;
#pragma unroll
    for (int i = 0; i < 8; ++i)
#pragma unroll
        for (int j = 0; j < 4; ++j)
#pragma unroll
            for (int r = 0; r < 4; ++r) {
                long m = bm + wr * 128 + i * 16 + quad * 4 + r;
                long n = bn + wc * 64 + j * 16 + l15;
                C[m * kS + n] = acc[i][j][r];
            }
}

// mix = attn @ ctx per batch (plain bf16): K' = S, single segment
__global__ __launch_bounds__(512, 2) void k_gemm_mix(const u16* __restrict__ attnb,
                                                     const u16* __restrict__ ctxT,
                                                     u16* __restrict__ Mixb) {
    const int l = blockIdx.x;
    const int xcd = l & 7, slot = l >> 3;
    const int z = xcd + ((slot >> 4) << 3);
    const int inner = slot & 15;
    const long bn = (long)(inner & 3) * 256;   // H tiles (4)
    const long bm = (long)(inner >> 2) * 256;  // T tiles (4)
    const u16* Ab = attnb + (long)z * kT * kS + bm * kS;
    const u16* Bb = ctxT + (long)z * kH * kS + bn * kS;
    f32x4 acc[8][4] = {};
    gemm_core<32, 32>(Ab, Ab, Ab, kS, Bb, Bb, Bb, kS, acc);
    u16* C = Mixb + (long)z * kT * kH;
    const int t = threadIdx.x, lane = t & 63, wave = t >> 6;
    const int wr = wave >> 2, wc = wave & 3, l15 = lane & 15, quad = lane >> 4;
#pragma unroll
    for (int i = 0; i < 8; ++i)
#pragma unroll
        for (int j = 0; j < 4; ++j)
#pragma unroll
            for (int r = 0; r < 4; ++r) {
                long m = bm + wr * 128 + i * 16 + quad * 4 + r;
                long n = bn + wc * 64 + j * 16 + l15;
                C[m * kH + n] = bf16_rne(acc[i][j][r]);
            }
}

// out = tanh([mix|q] @ lw^T + lb): K' = 2H, segs (mix,lw[:, :H]),(q,lw[:, H:])
__global__ __launch_bounds__(512, 2) void k_gemm_out(const u16* __restrict__ mixc,
                                                     const u16* __restrict__ qc,
                                                     const u16* __restrict__ lwb,
                                                     const float* __restrict__ bias,
                                                     float* __restrict__ Out) {
    const long bm = (long)blockIdx.y * 256, bn = (long)blockIdx.x * 256;
    f32x4 acc[8][4] = {};
    gemm_core<32, 16>(mixc + bm * kH, qc + bm * kH, qc + bm * kH, kH,
                      lwb + bn * 2 * kH, lwb + bn * 2 * kH + kH, lwb + bn * 2 * kH + kH,
                      2 * kH, acc);
    const int t = threadIdx.x, lane = t & 63, wave = t >> 6;
    const int wr = wave >> 2, wc = wave & 3, l15 = lane & 15, quad = lane >> 4;
#pragma unroll
    for (int j = 0; j < 4; ++j) {
        long n = bn + wc * 64 + j * 16 + l15;
        float bj = bias[n];
#pragma unroll
        for (int i = 0; i < 8; ++i)
#pragma unroll
            for (int r = 0; r < 4; ++r) {
                long m = bm + wr * 128 + i * 16 + quad * 4 + r;
                Out[m * kH + n] = tanhf(acc[i][j][r] + bj);
            }
    }
}

// ---------------- prepasses ----------------
__global__ __launch_bounds__(256) void split_f32(const float* __restrict__ src,
                                                 u16* __restrict__ hi, u16* __restrict__ lo,
                                                 long n4) {
    for (long i = (long)blockIdx.x * 256 + threadIdx.x; i < n4; i += (long)gridDim.x * 256) {
        float4 v = ((const float4*)src)[i];
        u16 h0, l0, h1, l1, h2, l2, h3, l3;
        split2(v.x, h0, l0); split2(v.y, h1, l1);
        split2(v.z, h2, l2); split2(v.w, h3, l3);
        ((ushort4*)hi)[i] = make_ushort4(h0, h1, h2, h3);
        ((ushort4*)lo)[i] = make_ushort4(l0, l1, l2, l3);
    }
}

__global__ __launch_bounds__(256) void cvt_f32(const float* __restrict__ src,
                                               u16* __restrict__ dst, long n4) {
    for (long i = (long)blockIdx.x * 256 + threadIdx.x; i < n4; i += (long)gridDim.x * 256) {
        float4 v = ((const float4*)src)[i];
        ((ushort4*)dst)[i] = make_ushort4(bf16_rne(v.x), bf16_rne(v.y),
                                          bf16_rne(v.z), bf16_rne(v.w));
    }
}

__global__ __launch_bounds__(256) void copy16(const uint4* __restrict__ src,
                                              uint4* __restrict__ dst, long n) {
    for (long i = (long)blockIdx.x * 256 + threadIdx.x; i < n; i += (long)gridDim.x * 256)
        dst[i] = src[i];
}

// bf16 [B,S,H] -> [B,H,S]
__global__ __launch_bounds__(256) void transpose_bf16(const u16* __restrict__ in,
                                                      u16* __restrict__ outp) {
    __shared__ u16 tile[64 * 72];
    const int t = threadIdx.x;
    const u16* src = in + (long)blockIdx.z * kS * kH + (long)(blockIdx.y * 64) * kH
                     + blockIdx.x * 64;
#pragma unroll
    for (int it = 0; it < 2; ++it) {
        int idx = it * 256 + t;
        int s = idx >> 3, hc = (idx & 7) << 3;
        uint4 v = *(const uint4*)(src + (long)s * kH + hc);
        const u16* pv = (const u16*)&v;
#pragma unroll
        for (int k = 0; k < 8; ++k) tile[(hc + k) * 72 + s] = pv[k];
    }
    __syncthreads();
    u16* dst = outp + (long)blockIdx.z * kH * kS + (long)(blockIdx.x * 64) * kS
               + blockIdx.y * 64;
#pragma unroll
    for (int it = 0; it < 2; ++it) {
        int idx = it * 256 + t;
        int h = idx >> 3, sc = (idx & 7) << 3;
        *(uint4*)(dst + (long)h * kS + sc) = *(const uint4*)&tile[h * 72 + sc];
    }
}

// ---------------- softmax over S, in place; emits bf16 copy ----------------
__global__ __launch_bounds__(256) void softmax_rows(float* __restrict__ P,
                                                    u16* __restrict__ Pb) {
    __shared__ float red[4];
    float* p = P + (long)blockIdx.x * kS;
    u16* pb = Pb + (long)blockIdx.x * kS;
    const int t = threadIdx.x;

    float4 v0 = ((const float4*)p)[t];
    float4 v1 = ((const float4*)p)[t + 256];

    float m = fmaxf(fmaxf(fmaxf(v0.x, v0.y), fmaxf(v0.z, v0.w)),
                    fmaxf(fmaxf(v1.x, v1.y), fmaxf(v1.z, v1.w)));
#pragma unroll
    for (int o = 32; o > 0; o >>= 1) m = fmaxf(m, __shfl_xor(m, o));
    if ((t & 63) == 0) red[t >> 6] = m;
    __syncthreads();
    m = fmaxf(fmaxf(red[0], red[1]), fmaxf(red[2], red[3]));
    __syncthreads();

    v0.x = expf(v0.x - m); v0.y = expf(v0.y - m);
    v0.z = expf(v0.z - m); v0.w = expf(v0.w - m);
    v1.x = expf(v1.x - m); v1.y = expf(v1.y - m);
    v1.z = expf(v1.z - m); v1.w = expf(v1.w - m);

    float s = v0.x + v0.y + v0.z + v0.w + v1.x + v1.y + v1.z + v1.w;
#pragma unroll
    for (int o = 32; o > 0; o >>= 1) s += __shfl_xor(s, o);
    if ((t & 63) == 0) red[t >> 6] = s;
    __syncthreads();
    s = red[0] + red[1] + red[2] + red[3];

    const float inv = 1.0f / s;
    v0.x *= inv; v0.y *= inv; v0.z *= inv; v0.w *= inv;
    v1.x *= inv; v1.y *= inv; v1.z *= inv; v1.w *= inv;

    ((float4*)p)[t]       = v0;
    ((float4*)p)[t + 256] = v1;
    ((ushort4*)pb)[t]       = make_ushort4(bf16_rne(v0.x), bf16_rne(v0.y),
                                           bf16_rne(v0.z), bf16_rne(v0.w));
    ((ushort4*)pb)[t + 256] = make_ushort4(bf16_rne(v1.x), bf16_rne(v1.y),
                                           bf16_rne(v1.z), bf16_rne(v1.w));
}

// ---------------------------------------------------------------------------
extern "C" void kernel_launch(void* const* d_in, const int* in_sizes, int n_in,
                              void* d_out, int out_size, void* d_ws, size_t ws_size,
                              hipStream_t stream) {
    (void)in_sizes; (void)n_in; (void)out_size; (void)ws_size;

    const float* outp = (const float*)d_in[0];  // [B,T,H]
    const float* ctx  = (const float*)d_in[1];  // [B,S,H]
    const float* aw   = (const float*)d_in[2];  // [H,H]
    const float* lw   = (const float*)d_in[3];  // [H,2H]
    const float* lb   = (const float*)d_in[4];  // [H]

    float* out  = (float*)d_out;
    float* attn = out + NTH;

    u16* ws = (u16*)d_ws;
    u16* ctx_hi = ws;
    u16* ctx_lo = ws + NSH;
    u16* q_hi = (u16*)out;
    u16* q_lo = q_hi + NTH;
    u16* oh  = (u16*)attn;
    u16* ol  = oh + NTH;
    u16* awh = ol + NTH;
    u16* awl = awh + (long)kH * kH;
    u16* ctxT  = ws + NSH;
    u16* attnb = ws;
    u16* mixb  = q_lo;
    u16* q_c   = ws;
    u16* mix_c = ws + NTH;
    u16* lwb   = ws + 2 * NTH;

    split_f32<<<2048, 256, 0, stream>>>(ctx, ctx_hi, ctx_lo, NSH / 4);
    split_f32<<<2048, 256, 0, stream>>>(outp, oh, ol, NTH / 4);
    split_f32<<<1024, 256, 0, stream>>>(aw, awh, awl, (long)kH * kH / 4);

    k_gemm_q<<<dim3(kH / 256, (kB * kT) / 256), 512, 0, stream>>>(oh, ol, awh, awl,
                                                                  q_hi, q_lo);
    k_gemm_logits<<<512, 512, 0, stream>>>(q_hi, q_lo, ctx_hi, ctx_lo, attn);

    transpose_bf16<<<dim3(kH / 64, kS / 64, kB), 256, 0, stream>>>(ctx_hi, ctxT);
    softmax_rows<<<kB * kT, 256, 0, stream>>>(attn, attnb);

    k_gemm_mix<<<256, 512, 0, stream>>>(attnb, ctxT, mixb);

    copy16<<<2048, 256, 0, stream>>>((const uint4*)q_hi, (uint4*)ws, (2 * NTH) / 8);
    cvt_f32<<<2048, 256, 0, stream>>>(lw, lwb, (long)kH * 2 * kH / 4);

    k_gemm_out<<<dim3(kH / 256, (kB * kT) / 256), 512, 0, stream>>>(mix_c, q_c, lwb, lb, out);
}